// Round 3
// baseline (179.241 us; speedup 1.0000x reference)
//
#include <hip/hip_runtime.h>
#include <math.h>

#define IMG_OUT 64
#define NZ 128          // internal z resolution
#define NF 64           // internal fine freq channels
#define BAND 16         // evaluated channels per (pixel,z)

__global__ __launch_bounds__(512) void cube_sim_kernel(
    const float* __restrict__ freqs,
    const float* __restrict__ p_incl,
    const float* __restrict__ p_rot,
    const float* __restrict__ p_lb,
    const float* __restrict__ p_vshift,
    const float* __restrict__ p_vmax,
    const float* __restrict__ p_rturn,
    const float* __restrict__ p_i0,
    const float* __restrict__ p_rd,
    const float* __restrict__ p_hz,
    float* __restrict__ out)
{
    const int t    = threadIdx.x;          // 0..511
    const int w    = t >> 6;               // wave 0..7
    const int lane = t & 63;
    const int p    = w >> 1;               // internal pixel 0..3
    const int iz   = ((w & 1) << 6) | lane; // z index 0..127
    const int xo   = blockIdx.x;
    const int yo   = blockIdx.y;

    __shared__ float s_acc[NF];            // pooled fine spectrum (all 4 pixels)
    if (t < NF) s_acc[t] = 0.0f;

    // ---- scalars ----
    const float incl   = p_incl[0];
    const float rot    = p_rot[0];
    const float lb     = p_lb[0];
    const float vshift = p_vshift[0];
    const float vmax   = p_vmax[0];
    const float rturn  = p_rturn[0];
    const float i0     = p_i0[0];
    const float rd     = p_rd[0];
    const float hz     = p_hz[0];

    const float LOG2E = 1.4426950408889634f;
    const float ci = cosf(incl), si = sinf(incl);
    const float cr = cosf(rot),  sr = sinf(rot);

    const float C_KMS = 299792.458f;
    const float F0    = 230.538f;
    const float f_lo  = freqs[0];
    const float df    = (freqs[15] - f_lo) * (1.0f / 63.0f);
    const float beta  = C_KMS * df / F0;                        // km/s per fine channel
    const float alpha = C_KMS * (F0 - f_lo + 2.0f * df) / F0 - vshift;
    const float inv_beta = 1.0f / beta;

    const float sgs  = sqrtf(LOG2E) / lb;   // d' = d_kms * sgs -> G = exp2(-d'^2)
    const float bp   = beta * sgs;          // channel pitch in d' units
    const float bp16 = 16.0f * bp;

    const float step = 2000.0f / 127.0f;
    const float inv_rturn = 1.0f / rturn;
    const float inv_rd = 1.0f / rd;
    const float inv_hz = 1.0f / hz;
    const float two_over_pi = 0.636619772367581f;

    __syncthreads();   // s_acc initialized

    // ---- geometry for this (pixel, z) point ----
    const float x = -1000.0f + (float)(2 * xo + (p >> 1)) * step;
    const float y = -1000.0f + (float)(2 * yo + (p & 1)) * step;
    const float z = -1000.0f + (float)iz * step;

    const float rx = cr * x - sr * y;
    const float u  = sr * x + cr * y;
    const float ry = ci * u - si * z;
    const float rz = si * u + ci * z;

    const float r2      = rx * rx + ry * ry + 1e-12f;
    const float inv_rad = __builtin_amdgcn_rsqf(r2);
    const float rad     = r2 * inv_rad;
    const float v_abs   = vmax * two_over_pi * atanf(rad * inv_rturn);
    const float v       = -si * v_abs * rx * inv_rad;           // v_los
    const float A = (-rad * inv_rd - fabsf(rz) * inv_hz) * LOG2E; // log2 intensity

    int f0 = (int)rintf((alpha - v) * inv_beta);
    f0 = min(max(f0, 8), 56);
    const int base = f0 - 8;                                    // band start in [0,48]
    const float W  = sgs * fmaf(-beta, (float)base, alpha - v); // d' at band offset 0

    // stagger start so concurrent lanes hit different channels
    const int   l15 = lane & 15;
    const float Wl  = fmaf(-bp, (float)l15, W);

    // ---- band evaluation + scatter (16 exp2, 16 ds_add_f32 total) ----
    #pragma unroll
    for (int j = 0; j < BAND; ++j) {
        const int lj = l15 + j;
        float d = fmaf(-bp, (float)j, Wl);
        d = (lj >= 16) ? (d + bp16) : d;          // wrap back into band
        const float wv = fmaf(-d, d, A);          // A - d'^2
        const float e  = __builtin_amdgcn_exp2f(wv);
        atomicAdd(&s_acc[base + (lj & 15)], e);
    }
    __syncthreads();

    // ---- pool 4 freq sub-channels, scale, write ----
    if (t < 16) {
        const float s = s_acc[4 * t] + s_acc[4 * t + 1]
                      + s_acc[4 * t + 2] + s_acc[4 * t + 3];
        const float scale = i0 * 0.0625f / sqrtf(6.283185307179586f * lb * lb);
        out[t * (IMG_OUT * IMG_OUT) + xo * IMG_OUT + yo] = s * scale;
    }
}

extern "C" void kernel_launch(void* const* d_in, const int* in_sizes, int n_in,
                              void* d_out, int out_size, void* d_ws, size_t ws_size,
                              hipStream_t stream) {
    (void)in_sizes; (void)n_in; (void)d_ws; (void)ws_size; (void)out_size;
    const float* freqs  = (const float*)d_in[0];
    const float* incl   = (const float*)d_in[1];
    const float* rot    = (const float*)d_in[2];
    const float* lb     = (const float*)d_in[3];
    const float* vshift = (const float*)d_in[4];
    const float* vmax   = (const float*)d_in[5];
    const float* rturn  = (const float*)d_in[6];
    const float* i0     = (const float*)d_in[7];
    const float* rd     = (const float*)d_in[8];
    const float* hz     = (const float*)d_in[9];
    float* out = (float*)d_out;

    dim3 grid(IMG_OUT, IMG_OUT);
    dim3 block(512);
    hipLaunchKernelGGL(cube_sim_kernel, grid, block, 0, stream,
                       freqs, incl, rot, lb, vshift, vmax, rturn, i0, rd, hz, out);
}

// Round 4
// 16.562 us; speedup vs baseline: 10.8226x; 10.8226x over previous
//
#include <hip/hip_runtime.h>
#include <math.h>

#define IMG_OUT 64
#define BAND 16

__global__ __launch_bounds__(64) void cube_sim_kernel(
    const float* __restrict__ freqs,
    const float* __restrict__ p_incl,
    const float* __restrict__ p_rot,
    const float* __restrict__ p_lb,
    const float* __restrict__ p_vshift,
    const float* __restrict__ p_vmax,
    const float* __restrict__ p_rturn,
    const float* __restrict__ p_i0,
    const float* __restrict__ p_rd,
    const float* __restrict__ p_hz,
    float* __restrict__ out)
{
    const int lane = threadIdx.x;      // 0..63
    const int xo = blockIdx.x;
    const int yo = blockIdx.y;
    const int p  = lane >> 4;          // internal pixel 0..3
    const int zb = lane & 15;          // z-block (8 z each)

    __shared__ float s_band[64][BAND + 1];   // stride 17 -> conflict-free

    // ---- scalars ----
    const float incl   = p_incl[0];
    const float rot    = p_rot[0];
    const float lb     = p_lb[0];
    const float vshift = p_vshift[0];
    const float vmx    = p_vmax[0];
    const float rturn  = p_rturn[0];
    const float i0     = p_i0[0];
    const float rd     = p_rd[0];
    const float hz     = p_hz[0];

    const float LOG2E = 1.4426950408889634f;
    const float ci = cosf(incl), si = sinf(incl);
    const float cr = cosf(rot),  sr = sinf(rot);

    const float C_KMS = 299792.458f;
    const float F0    = 230.538f;
    const float f_lo  = freqs[0];
    const float df    = (freqs[15] - f_lo) * (1.0f / 63.0f);
    const float beta  = C_KMS * df / F0;                       // km/s per fine channel
    const float alpha = C_KMS * (F0 - f_lo + 2.0f * df) / F0 - vshift;
    const float inv_beta = 1.0f / beta;

    const float sgs = sqrtf(LOG2E) / lb;   // d' = d_kms*sgs -> G = exp2(-d'^2)
    const float bp  = beta * sgs;          // channel pitch in d' units

    const float step = 2000.0f / 127.0f;
    const float inv_rturn = 1.0f / rturn;
    const float cA_r = -LOG2E / rd;        // log2-intensity coefficients
    const float cA_z = -LOG2E / hz;
    const float two_over_pi = 0.636619772367581f;

    // ---- geometry for this lane's 8 z-points (all registers) ----
    const float x = -1000.0f + (float)(2 * xo + (p >> 1)) * step;
    const float y = -1000.0f + (float)(2 * yo + (p & 1)) * step;
    const float rx  = cr * x - sr * y;
    const float u   = sr * x + cr * y;
    const float crx = -si * vmx * two_over_pi * rx;   // v_los = crx*atan(rad/rt)/rad

    float v[8], A[8];
    #pragma unroll
    for (int k = 0; k < 8; ++k) {
        const float z  = -1000.0f + (float)(zb * 8 + k) * step;
        const float ry = ci * u - si * z;
        const float rz = si * u + ci * z;
        const float r2 = rx * rx + ry * ry + 1e-12f;
        const float ir = __builtin_amdgcn_rsqf(r2);
        const float rad = r2 * ir;
        v[k] = crx * atanf(rad * inv_rturn) * ir;
        A[k] = fmaf(rad, cA_r, fabsf(rz) * cA_z);     // log2 intensity (i0 excluded)
    }

    // ---- band base from v_los range midpoint ----
    float vlo = v[0], vhi = v[0];
    #pragma unroll
    for (int k = 1; k < 8; ++k) { vlo = fminf(vlo, v[k]); vhi = fmaxf(vhi, v[k]); }
    int f0 = (int)rintf((alpha - 0.5f * (vlo + vhi)) * inv_beta);
    f0 = min(max(f0, 8), 56);
    const int base = f0 - 8;                          // [0,48]
    const float Wb = fmaf(-beta, (float)base, alpha); // diff at channel `base`, km/s

    // ---- 8z x 16ch KDE, register-resident ----
    float acc[BAND];
    #pragma unroll
    for (int j = 0; j < BAND; ++j) acc[j] = 0.0f;

    #pragma unroll
    for (int k = 0; k < 8; ++k) {
        const float Wk = sgs * (Wb - v[k]);
        const float Ak = A[k];
        #pragma unroll
        for (int j = 0; j < BAND; ++j) {
            const float d  = fmaf(-bp, (float)j, Wk);
            const float wv = fmaf(-d, d, Ak);         // A - d'^2
            acc[j] += __builtin_amdgcn_exp2f(wv);
        }
    }

    // ---- publish band, then gather per channel (plain DS only) ----
    #pragma unroll
    for (int j = 0; j < BAND; ++j) s_band[lane][j] = acc[j];
    __syncthreads();

    const int c = lane;                               // fine channel 0..63
    float s = 0.0f;
    #pragma unroll
    for (int l = 0; l < 64; ++l) {
        const int bl  = __builtin_amdgcn_readlane(base, l);
        const int off = c - bl;
        const float val = s_band[l][off & 15];        // broadcast-friendly read
        s += ((unsigned)off < 16u) ? val : 0.0f;
    }

    // ---- pool 4 freq sub-channels, scale, write ----
    s += __shfl_xor(s, 1);
    s += __shfl_xor(s, 2);
    if ((c & 3) == 0) {
        const float scale = i0 * 0.0625f / sqrtf(6.283185307179586f * lb * lb);
        out[(c >> 2) * (IMG_OUT * IMG_OUT) + xo * IMG_OUT + yo] = s * scale;
    }
}

extern "C" void kernel_launch(void* const* d_in, const int* in_sizes, int n_in,
                              void* d_out, int out_size, void* d_ws, size_t ws_size,
                              hipStream_t stream) {
    (void)in_sizes; (void)n_in; (void)d_ws; (void)ws_size; (void)out_size;
    const float* freqs  = (const float*)d_in[0];
    const float* incl   = (const float*)d_in[1];
    const float* rot    = (const float*)d_in[2];
    const float* lb     = (const float*)d_in[3];
    const float* vshift = (const float*)d_in[4];
    const float* vmax   = (const float*)d_in[5];
    const float* rturn  = (const float*)d_in[6];
    const float* i0     = (const float*)d_in[7];
    const float* rd     = (const float*)d_in[8];
    const float* hz     = (const float*)d_in[9];
    float* out = (float*)d_out;

    dim3 grid(IMG_OUT, IMG_OUT);
    dim3 block(64);
    hipLaunchKernelGGL(cube_sim_kernel, grid, block, 0, stream,
                       freqs, incl, rot, lb, vshift, vmax, rturn, i0, rd, hz, out);
}